// Round 2
// baseline (1440.593 us; speedup 1.0000x reference)
//
#include <hip/hip_runtime.h>

// ---------------------------------------------------------------------------
// Decoder (GRU, T=50 steps) on MI355X.
// Round 1: fuse the 50-step scan into ONE persistent kernel.
//   - 128 blocks x 1 wave; block = 32 batch rows x 32 hidden cols (96 gate cols).
//   - Whh slice (96x512 bf16 = 96KB) persistent in LDS across all steps.
//   - h slice (32x512 = 32KB) restaged per step; XOR-swizzled LDS, ds_read_b128.
//   - gates fused in-kernel; one device-scope grid barrier per step.
//   - ghc folded into gx_all for r,z gates (gx-GEMM epilogue add2).
// Dims: V=10004 E=300 SH=1024 H=512 G=1024 B=128 T=50.
// ---------------------------------------------------------------------------

typedef __bf16 bf16x8 __attribute__((ext_vector_type(8)));
typedef float f32x4 __attribute__((ext_vector_type(4)));

// ---------------- fp32 -> bf16 (padded) conversion -------------------------
__global__ void cvt_kernel(const float* __restrict__ src, int srows, int scols,
                           int sstride, int soff,
                           __bf16* __restrict__ dst, int drows, int dcols) {
    int idx = blockIdx.x * 256 + threadIdx.x;
    int total = drows * dcols;
    if (idx >= total) return;
    int r = idx / dcols, c = idx % dcols;
    float v = 0.0f;
    if (r < srows && c < scols) v = src[(size_t)r * sstride + soff + c];
    dst[idx] = (__bf16)v;
}

// ---------------- embedding gather -> bf16 [t*128+b][320] ------------------
__global__ void emb_kernel(const int* __restrict__ x, const float* __restrict__ emb,
                           __bf16* __restrict__ embbf) {
    int m = blockIdx.x;            // m = t*128 + b
    int t = m >> 7, b = m & 127;
    int tok = x[b * 50 + t];
    const float* src = emb + (size_t)tok * 300;
    for (int i = threadIdx.x; i < 320; i += 64) {
        float v = (i < 300) ? src[i] : 0.0f;
        embbf[(size_t)m * 320 + i] = (__bf16)v;
    }
}

// ---------------- generic bf16 MFMA GEMM: C = A @ B^T ----------------------
struct GemmParams {
    const __bf16* A; int lda;
    const __bf16* B; int ldb; int Brows;
    int K;
    const float* bias;
    float* outF; int ldo; int Nstore;
    __bf16* outBf;
    const __bf16* res;     // EPI 2: residual (emb_bf), row-indexed like A
    const float* add2;     // EPI 0: extra addend, row (r&127), col-limited
    int ld2; int add2lim;
};

// EPI: 0 = f32 store (+bias, +add2[r&127] for c<add2lim)   (ghc, gx)
//      1 = tanh, dual f32+bf16 store                        (ses)
//      2 = bias + residual, bf16 store, row remap           (o)
//      3 = plain f32 store with col guard                   (logits)
template <int EPI>
__launch_bounds__(256, 2)
__global__ void gemm_bt(GemmParams p) {
    __shared__ __bf16 As[128][40];
    __shared__ __bf16 Bs[128][40];

    const int tid = threadIdx.x;
    const int lane = tid & 63;
    const int wid = tid >> 6;
    const int wr = wid >> 1, wc = wid & 1;
    const int m0 = blockIdx.x * 128, c0 = blockIdx.y * 128;
    const int lrow = lane & 15;
    const int kq = lane >> 4;

    f32x4 acc[4][4];
#pragma unroll
    for (int i = 0; i < 4; ++i)
#pragma unroll
        for (int j = 0; j < 4; ++j) acc[i][j] = (f32x4){0.f, 0.f, 0.f, 0.f};

    for (int kb = 0; kb < p.K; kb += 32) {
#pragma unroll
        for (int i = 0; i < 2; ++i) {
            int chunk = i * 256 + tid;
            int row = chunk >> 2;
            int cc = (chunk & 3) * 8;
            bf16x8 va = *reinterpret_cast<const bf16x8*>(
                p.A + (size_t)(m0 + row) * p.lda + kb + cc);
            *reinterpret_cast<bf16x8*>(&As[row][cc]) = va;
            bf16x8 vb;
#pragma unroll
            for (int q = 0; q < 8; ++q) vb[q] = (__bf16)0.0f;
            int grow = c0 + row;
            if (grow < p.Brows)
                vb = *reinterpret_cast<const bf16x8*>(
                    p.B + (size_t)grow * p.ldb + kb + cc);
            *reinterpret_cast<bf16x8*>(&Bs[row][cc]) = vb;
        }
        __syncthreads();

        bf16x8 af[4], bfr[4];
#pragma unroll
        for (int m = 0; m < 4; ++m)
            af[m] = *reinterpret_cast<const bf16x8*>(&As[wr * 64 + m * 16 + lrow][kq * 8]);
#pragma unroll
        for (int n = 0; n < 4; ++n)
            bfr[n] = *reinterpret_cast<const bf16x8*>(&Bs[wc * 64 + n * 16 + lrow][kq * 8]);
#pragma unroll
        for (int m = 0; m < 4; ++m)
#pragma unroll
            for (int n = 0; n < 4; ++n)
                acc[m][n] = __builtin_amdgcn_mfma_f32_16x16x32_bf16(
                    af[m], bfr[n], acc[m][n], 0, 0, 0);
        __syncthreads();
    }

#pragma unroll
    for (int m = 0; m < 4; ++m) {
#pragma unroll
        for (int n = 0; n < 4; ++n) {
#pragma unroll
            for (int i = 0; i < 4; ++i) {
                int r = m0 + wr * 64 + m * 16 + kq * 4 + i;
                int c = c0 + wc * 64 + n * 16 + lrow;
                float v = acc[m][n][i];
                if constexpr (EPI == 0) {
                    if (c < p.Nstore) {
                        if (p.bias) v += p.bias[c];
                        if (p.add2 && c < p.add2lim)
                            v += p.add2[(size_t)(r & 127) * p.ld2 + c];
                        p.outF[(size_t)r * p.ldo + c] = v;
                    }
                } else if constexpr (EPI == 1) {
                    v = tanhf(v + p.bias[c]);
                    p.outF[(size_t)r * p.ldo + c] = v;
                    p.outBf[(size_t)r * p.ldo + c] = (__bf16)v;
                } else if constexpr (EPI == 2) {
                    int ro = (r & 127) * 50 + (r >> 7);
                    if (c < 300) {
                        v += p.bias[c] + (float)p.res[(size_t)r * 320 + c];
                        p.outBf[(size_t)ro * 320 + c] = (__bf16)v;
                    } else if (c < 320) {
                        p.outBf[(size_t)ro * 320 + c] = (__bf16)0.0f;
                    }
                } else {
                    if (c < p.Nstore) p.outF[(size_t)r * p.ldo + c] = v;
                }
            }
        }
    }
}

// ---------------- persistent fused scan kernel -----------------------------
#define SCAN_NB 128
__launch_bounds__(64, 1)
__global__ void scan_kernel(const __bf16* __restrict__ Whh_a,   // [3072][512]
                            const float* __restrict__ gx_all,   // [50][128][3072] (r,z incl ghc)
                            const float* __restrict__ ghc,      // [128][3072]
                            const float* __restrict__ ses_f32,  // [128][512]
                            const __bf16* __restrict__ ses_bf,  // [128][512]
                            float* __restrict__ hf0, float* __restrict__ hf1,
                            __bf16* __restrict__ hb0, __bf16* __restrict__ hb1,
                            __bf16* __restrict__ hall,          // [6400][1024]
                            unsigned* __restrict__ cnt) {
    __shared__ char smem[131072];          // 96KB Whh slice + 32KB h slice
    char* BsB = smem;
    char* HsB = smem + 98304;
    const int lane = threadIdx.x;
    const int bid = blockIdx.x;
    const int q = bid >> 5;                // batch-row quarter (0..3)
    const int j0 = (bid & 31) * 32;        // hidden col base (0..992)
    const int r0 = q * 32;
    const int lrow = lane & 15, kq = lane >> 4;

    // ---- preload Whh_a rows {gate*1024 + j0 + rr}, XOR-swizzled ----
    for (int i = 0; i < 96; ++i) {
        int c = i * 64 + lane;             // 0..6143
        int brow = c >> 6, col16 = c & 63;
        int gate = brow >> 5, rr = brow & 31;
        bf16x8 v = *reinterpret_cast<const bf16x8*>(
            Whh_a + (size_t)(gate * 1024 + j0 + rr) * 512 + col16 * 8);
        *reinterpret_cast<bf16x8*>(BsB + brow * 1024 + ((col16 ^ (brow & 7)) << 4)) = v;
    }
    __syncthreads();

    f32x4 acc[2][6];
    for (int t = 0; t < 50; ++t) {
        const __bf16* hsrc = (t == 0) ? ses_bf : ((t & 1) ? hb1 : hb0);
        // ---- stage h rows r0..r0+32 into LDS (swizzled) ----
        for (int i = 0; i < 32; ++i) {
            int c = i * 64 + lane;         // 0..2047
            int hrow = c >> 6, col16 = c & 63;
            bf16x8 v = *reinterpret_cast<const bf16x8*>(
                hsrc + (size_t)(r0 + hrow) * 512 + col16 * 8);
            *reinterpret_cast<bf16x8*>(HsB + hrow * 1024 + ((col16 ^ (hrow & 7)) << 4)) = v;
        }
        __syncthreads();

#pragma unroll
        for (int m = 0; m < 2; ++m)
#pragma unroll
            for (int n = 0; n < 6; ++n) acc[m][n] = (f32x4){0.f, 0.f, 0.f, 0.f};

        for (int kb = 0; kb < 16; ++kb) {
            int kchunk = kb * 4 + kq;
            bf16x8 a[2], b[6];
#pragma unroll
            for (int m = 0; m < 2; ++m) {
                int row = m * 16 + lrow;
                a[m] = *reinterpret_cast<const bf16x8*>(
                    HsB + row * 1024 + ((kchunk ^ (row & 7)) << 4));
            }
#pragma unroll
            for (int n = 0; n < 6; ++n) {
                int brow = n * 16 + lrow;
                b[n] = *reinterpret_cast<const bf16x8*>(
                    BsB + brow * 1024 + ((kchunk ^ (brow & 7)) << 4));
            }
#pragma unroll
            for (int m = 0; m < 2; ++m)
#pragma unroll
                for (int n = 0; n < 6; ++n)
                    acc[m][n] = __builtin_amdgcn_mfma_f32_16x16x32_bf16(
                        a[m], b[n], acc[m][n], 0, 0, 0);
        }

        // ---- gates epilogue (n-tiles 0,1 = r; 2,3 = z; 4,5 = n) ----
        const float* hpf = (t == 0) ? ses_f32 : ((t & 1) ? hf1 : hf0);
        float*  hfd = ((t + 1) & 1) ? hf1 : hf0;
        __bf16* hbd = ((t + 1) & 1) ? hb1 : hb0;
        const float* gx = gx_all + (size_t)t * 128 * 3072;
#pragma unroll
        for (int m = 0; m < 2; ++m) {
#pragma unroll
            for (int g = 0; g < 2; ++g) {
                int j = j0 + g * 16 + lrow;
#pragma unroll
                for (int i = 0; i < 4; ++i) {
                    int b = r0 + m * 16 + kq * 4 + i;
                    size_t base = (size_t)b * 3072;
                    float pr = gx[base + j] + acc[m][g][i];
                    float pz = gx[base + 1024 + j] + acc[m][2 + g][i];
                    float gn = gx[base + 2048 + j];
                    float cn = ghc[base + 2048 + j];
                    float r = 1.0f / (1.0f + expf(-pr));
                    float z = 1.0f / (1.0f + expf(-pz));
                    float nn = tanhf(gn + r * (acc[m][4 + g][i] + cn));
                    float hf = (j < 512) ? hpf[(size_t)b * 512 + j]
                                         : ses_f32[(size_t)b * 512 + j - 512];
                    float hn = (1.0f - z) * nn + z * hf;
                    hall[(size_t)(t * 128 + b) * 1024 + j] = (__bf16)hn;
                    if (j < 512) {
                        hfd[(size_t)b * 512 + j] = hn;
                        hbd[(size_t)b * 512 + j] = (__bf16)hn;
                    }
                }
            }
        }

        // ---- grid barrier (device-scope, monotonic counter) ----
        if (t < 49) {
            if (lane == 0) {
                __hip_atomic_fetch_add(cnt, 1u, __ATOMIC_RELEASE, __HIP_MEMORY_SCOPE_AGENT);
                unsigned target = (unsigned)(t + 1) * SCAN_NB;
                while (__hip_atomic_load(cnt, __ATOMIC_ACQUIRE, __HIP_MEMORY_SCOPE_AGENT) < target)
                    __builtin_amdgcn_s_sleep(2);
            }
            __syncthreads();
        }
    }
}

// ---------------------------------------------------------------------------
extern "C" void kernel_launch(void* const* d_in, const int* in_sizes, int n_in,
                              void* d_out, int out_size, void* d_ws, size_t ws_size,
                              hipStream_t stream) {
    const float* ses_enc = (const float*)d_in[0];
    const int*   x       = (const int*)d_in[1];
    const float* emb     = (const float*)d_in[2];
    const float* Wih     = (const float*)d_in[3];
    const float* Whh     = (const float*)d_in[4];
    const float* bih     = (const float*)d_in[5];
    const float* bhh     = (const float*)d_in[6];
    const float* W1      = (const float*)d_in[7];
    const float* b1      = (const float*)d_in[8];
    const float* W2      = (const float*)d_in[9];
    const float* b2      = (const float*)d_in[10];
    const float* Wout    = (const float*)d_in[11];
    float* out = (float*)d_out;

    // ---- workspace layout (bytes) ----
    char* ws = (char*)d_ws;
    float*  ses_f32   = (float*)(ws + 0);          // 128*512*4
    __bf16* ses_bf    = (__bf16*)(ws + 262144);    // 128*512*2
    float*  ghc       = (float*)(ws + 393216);     // 128*3072*4
    float*  hbufs[2]  = {(float*)(ws + 3538944), (float*)(ws + 3801088)};
    __bf16* hbfs[2]   = {(__bf16*)(ws + 4063232), (__bf16*)(ws + 4194304)};
    __bf16* o_bf      = (__bf16*)(ws + 4325376);   // 6400*320*2
    __bf16* W1_bf     = (__bf16*)(ws + 8421376);   // 512*1024*2
    __bf16* Whh_a_bf  = (__bf16*)(ws + 9469952);   // 3072*512*2
    __bf16* Whh_b_bf  = (__bf16*)(ws + 12615680);  // 3072*512*2
    __bf16* Wih_bf    = (__bf16*)(ws + 15761408);  // 3072*320*2
    __bf16* W2_bf     = (__bf16*)(ws + 17727488);  // 300*1024*2
    __bf16* Wout_bf   = (__bf16*)(ws + 18341888);  // 10112*320*2
    __bf16* sesenc_bf = (__bf16*)(ws + 24813568);  // 128*1024*2
    unsigned* cnt     = (unsigned*)(ws + 25075712);

    // ---- d_out used as scratch for intermediates consumed before logits ----
    char* ob = (char*)d_out;
    float*  gx_all  = (float*)ob;                  // 50*128*3072*4 = 78,643,200
    __bf16* emb_bf  = (__bf16*)(ob + 80000000);    // 6400*320*2
    __bf16* hall_bf = (__bf16*)(ob + 88000000);    // 6400*1024*2

    dim3 blk(256);
    auto cvt = [&](const float* src, int sr, int sc, int ss, int so,
                   __bf16* dst, int dr, int dc) {
        int total = dr * dc;
        cvt_kernel<<<(total + 255) / 256, 256, 0, stream>>>(src, sr, sc, ss, so, dst, dr, dc);
    };
    cvt(W1,      512, 1024, 1024, 0,   W1_bf,     512, 1024);
    cvt(Whh,    3072,  512, 1024, 0,   Whh_a_bf, 3072,  512);
    cvt(Whh,    3072,  512, 1024, 512, Whh_b_bf, 3072,  512);
    cvt(Wih,    3072,  300,  300, 0,   Wih_bf,   3072,  320);
    cvt(W2,      300, 1024, 1024, 0,   W2_bf,     300, 1024);
    cvt(Wout,  10004,  300,  300, 0,   Wout_bf, 10112,  320);
    cvt(ses_enc, 128, 1024, 1024, 0,   sesenc_bf, 128, 1024);
    emb_kernel<<<6400, 64, 0, stream>>>(x, emb, emb_bf);
    hipMemsetAsync(cnt, 0, 4, stream);

    GemmParams P;

    // ses = tanh(ses_enc @ W1^T + b1)  -> f32 + bf16
    P = {sesenc_bf, 1024, W1_bf, 1024, 512, 1024, b1, ses_f32, 512, 512, ses_bf, nullptr};
    gemm_bt<1><<<dim3(1, 4), blk, 0, stream>>>(P);

    // ghc = ses @ Whh[:,512:]^T + bhh   (step-invariant hidden contribution)
    P = {ses_bf, 512, Whh_b_bf, 512, 3072, 512, bhh, ghc, 3072, 3072, nullptr, nullptr};
    gemm_bt<0><<<dim3(1, 24), blk, 0, stream>>>(P);

    // gx_all = emb @ Wih^T + bih  (+ ghc for r,z slices only)
    P = {emb_bf, 320, Wih_bf, 320, 3072, 320, bih, gx_all, 3072, 3072, nullptr, nullptr,
         ghc, 3072, 2048};
    gemm_bt<0><<<dim3(50, 24), blk, 0, stream>>>(P);

    // ---- fused persistent scan (replaces 100 launches) ----
    scan_kernel<<<SCAN_NB, 64, 0, stream>>>(
        Whh_a_bf, gx_all, ghc, ses_f32, ses_bf,
        hbufs[0], hbufs[1], hbfs[0], hbfs[1], hall_bf, cnt);

    // o = hnew @ W2^T + b2 + emb   -> bf16, rows remapped (t,b) -> (b,t)
    P = {hall_bf, 1024, W2_bf, 1024, 300, 1024, b2, nullptr, 0, 300, o_bf, emb_bf};
    gemm_bt<2><<<dim3(50, 3), blk, 0, stream>>>(P);

    // logits = o @ Wout^T  -> d_out f32 (overwrites all scratch regions)
    P = {o_bf, 320, Wout_bf, 320, 10112, 320, nullptr, out, 10004, 10004, nullptr, nullptr};
    gemm_bt<3><<<dim3(50, 79), blk, 0, stream>>>(P);

    (void)in_sizes; (void)n_in; (void)out_size; (void)ws_size;
}

// Round 3
// 906.657 us; speedup vs baseline: 1.5889x; 1.5889x over previous
//
#include <hip/hip_runtime.h>

// ---------------------------------------------------------------------------
// Decoder (GRU, T=50 steps) on MI355X.
// Round 2: latency-optimized persistent scan.
//   - Swapped-operand MFMA in scan: D[col]=batch -> all epilogue traffic
//     coalesced in b. gx/ghc/sesT/h-carry stored transposed [c][128b].
//   - 128 blocks x 256 thr (4 waves); Whh slice 96KB persistent in LDS,
//     XOR-swizzled; h staged 32KB/step from linear [b][k] bf16 copy.
//   - Early-issued coalesced epilogue loads (20/lane, full MLP).
//   - 8-counter cacheline-spaced grid barrier + explicit agent fences.
// Dims: V=10004 E=300 SH=1024 H=512 G=1024 B=128 T=50.
// ---------------------------------------------------------------------------

typedef __bf16 bf16x8 __attribute__((ext_vector_type(8)));
typedef float f32x4 __attribute__((ext_vector_type(4)));

// ---------------- fp32 -> bf16 (padded) conversion -------------------------
__global__ void cvt_kernel(const float* __restrict__ src, int srows, int scols,
                           int sstride, int soff,
                           __bf16* __restrict__ dst, int drows, int dcols) {
    int idx = blockIdx.x * 256 + threadIdx.x;
    int total = drows * dcols;
    if (idx >= total) return;
    int r = idx / dcols, c = idx % dcols;
    float v = 0.0f;
    if (r < srows && c < scols) v = src[(size_t)r * sstride + soff + c];
    dst[idx] = (__bf16)v;
}

// ---------------- embedding gather -> bf16 [t*128+b][320] ------------------
__global__ void emb_kernel(const int* __restrict__ x, const float* __restrict__ emb,
                           __bf16* __restrict__ embbf) {
    int m = blockIdx.x;            // m = t*128 + b
    int t = m >> 7, b = m & 127;
    int tok = x[b * 50 + t];
    const float* src = emb + (size_t)tok * 300;
    for (int i = threadIdx.x; i < 320; i += 64) {
        float v = (i < 300) ? src[i] : 0.0f;
        embbf[(size_t)m * 320 + i] = (__bf16)v;
    }
}

// ---------------- generic bf16 MFMA GEMM: C = A @ B^T ----------------------
struct GemmParams {
    const __bf16* A; int lda;
    const __bf16* B; int ldb; int Brows;
    int K;
    const float* bias;
    float* outF; int ldo; int Nstore;   // EPI4: ldo = t-stride
    __bf16* outBf;
    const __bf16* res;     // EPI 2: residual (emb_bf), row-indexed like A
    const float* add2;     // EPI 4: transposed addend [r][128]
    int ld2; int add2lim;
};

// EPI: 1 = tanh, bf16 normal + f32 TRANSPOSED store        (ses)
//      2 = bias + residual, bf16 store, row remap          (o)
//      3 = plain f32 store with col guard                  (logits)
//      4 = transposed f32 store: out[(c>>7)*ldo + r*128 + (c&127)]
//          (+bias[r], +add2[r*128+(c&127)] if r<add2lim)   (ghcT, gxT)
template <int EPI>
__launch_bounds__(256, 2)
__global__ void gemm_bt(GemmParams p) {
    __shared__ __bf16 As[128][40];
    __shared__ __bf16 Bs[128][40];

    const int tid = threadIdx.x;
    const int lane = tid & 63;
    const int wid = tid >> 6;
    const int wr = wid >> 1, wc = wid & 1;
    const int m0 = blockIdx.x * 128, c0 = blockIdx.y * 128;
    const int lrow = lane & 15;
    const int kq = lane >> 4;

    f32x4 acc[4][4];
#pragma unroll
    for (int i = 0; i < 4; ++i)
#pragma unroll
        for (int j = 0; j < 4; ++j) acc[i][j] = (f32x4){0.f, 0.f, 0.f, 0.f};

    for (int kb = 0; kb < p.K; kb += 32) {
#pragma unroll
        for (int i = 0; i < 2; ++i) {
            int chunk = i * 256 + tid;
            int row = chunk >> 2;
            int cc = (chunk & 3) * 8;
            bf16x8 va = *reinterpret_cast<const bf16x8*>(
                p.A + (size_t)(m0 + row) * p.lda + kb + cc);
            *reinterpret_cast<bf16x8*>(&As[row][cc]) = va;
            bf16x8 vb;
#pragma unroll
            for (int q = 0; q < 8; ++q) vb[q] = (__bf16)0.0f;
            int grow = c0 + row;
            if (grow < p.Brows)
                vb = *reinterpret_cast<const bf16x8*>(
                    p.B + (size_t)grow * p.ldb + kb + cc);
            *reinterpret_cast<bf16x8*>(&Bs[row][cc]) = vb;
        }
        __syncthreads();

        bf16x8 af[4], bfr[4];
#pragma unroll
        for (int m = 0; m < 4; ++m)
            af[m] = *reinterpret_cast<const bf16x8*>(&As[wr * 64 + m * 16 + lrow][kq * 8]);
#pragma unroll
        for (int n = 0; n < 4; ++n)
            bfr[n] = *reinterpret_cast<const bf16x8*>(&Bs[wc * 64 + n * 16 + lrow][kq * 8]);
#pragma unroll
        for (int m = 0; m < 4; ++m)
#pragma unroll
            for (int n = 0; n < 4; ++n)
                acc[m][n] = __builtin_amdgcn_mfma_f32_16x16x32_bf16(
                    af[m], bfr[n], acc[m][n], 0, 0, 0);
        __syncthreads();
    }

#pragma unroll
    for (int m = 0; m < 4; ++m) {
#pragma unroll
        for (int n = 0; n < 4; ++n) {
#pragma unroll
            for (int i = 0; i < 4; ++i) {
                int r = m0 + wr * 64 + m * 16 + kq * 4 + i;
                int c = c0 + wc * 64 + n * 16 + lrow;
                float v = acc[m][n][i];
                if constexpr (EPI == 1) {
                    v = tanhf(v + p.bias[c]);
                    p.outBf[(size_t)r * p.ldo + c] = (__bf16)v;
                    p.outF[(size_t)c * 128 + r] = v;          // ses_T[hcol][b]
                } else if constexpr (EPI == 2) {
                    int ro = (r & 127) * 50 + (r >> 7);
                    if (c < 300) {
                        v += p.bias[c] + (float)p.res[(size_t)r * 320 + c];
                        p.outBf[(size_t)ro * 320 + c] = (__bf16)v;
                    } else if (c < 320) {
                        p.outBf[(size_t)ro * 320 + c] = (__bf16)0.0f;
                    }
                } else if constexpr (EPI == 3) {
                    if (c < p.Nstore) p.outF[(size_t)r * p.ldo + c] = v;
                } else {  // EPI == 4
                    if (c < p.Brows) {
                        float v2 = v + p.bias[r];
                        if (p.add2 && r < p.add2lim)
                            v2 += p.add2[(size_t)r * 128 + (c & 127)];
                        p.outF[(size_t)(c >> 7) * p.ldo + (size_t)r * 128 + (c & 127)] = v2;
                    }
                }
            }
        }
    }
}

// ---------------- persistent fused scan kernel -----------------------------
// Swapped MFMA: A=Whh rows (gate-rows), B=h rows (batch), D[gaterow][batch].
#define SCAN_NB 128
__launch_bounds__(256, 1)
__global__ void scan_kernel(const __bf16* __restrict__ Whh_a,   // [3072][512]
                            const float* __restrict__ gxT,      // [50][3072][128]
                            const float* __restrict__ ghcT,     // [3072][128]
                            const float* __restrict__ sesT,     // [512][128] f32
                            const __bf16* __restrict__ ses_bf,  // [128][512]
                            float* __restrict__ hT0, float* __restrict__ hT1,  // [512][128]
                            __bf16* __restrict__ hb0, __bf16* __restrict__ hb1,// [128][512]
                            __bf16* __restrict__ hall,          // [6400][1024]
                            unsigned* __restrict__ cnt) {       // 8 ctr @ stride 32
    __shared__ char smem[131072];          // 96KB Whh + 32KB Hs, XOR-swizzled
    char* Ws = smem;
    char* Hs = smem + 98304;
    const int tid = threadIdx.x;
    const int lane = tid & 63;
    const int wid = tid >> 6;
    const int wr = wid >> 1, wc = wid & 1;
    const int bid = blockIdx.x;
    const int q = bid >> 5;                // batch quarter
    const int j0 = (bid & 31) * 32;        // hidden-col base (0..992)
    const int lrow = lane & 15, kq = lane >> 4;
    const bool writes_h = (j0 < 512);

    // ---- stage Whh slice once: rows {g*1024 + j0 + jj}, swizzled ----
    for (int it = 0; it < 24; ++it) {
        int c = it * 256 + tid;            // 0..6143 (16B chunks)
        int rl = c >> 6, o16 = c & 63;
        int g = rl >> 5, jj = rl & 31;
        bf16x8 v = *reinterpret_cast<const bf16x8*>(
            Whh_a + (size_t)(g * 1024 + j0 + jj) * 512 + o16 * 8);
        *reinterpret_cast<bf16x8*>(Ws + rl * 1024 + ((o16 * 16) ^ ((rl & 7) << 4))) = v;
    }

    const int b_g = q * 32 + wc * 16 + lrow;   // global batch col for this lane
    const int jbase = j0 + wr * 16 + kq * 4;   // global j base for this lane

    for (int t = 0; t < 50; ++t) {
        // ---- stage h slice [32 b][512 k] from linear bf16, swizzled ----
        const __bf16* hsrc = (t == 0) ? ses_bf : ((t & 1) ? hb0 : hb1);
        for (int it = 0; it < 8; ++it) {
            int c = it * 256 + tid;        // 0..2047
            int rl = c >> 6, o16 = c & 63;
            bf16x8 v = *reinterpret_cast<const bf16x8*>(
                hsrc + (size_t)(q * 32 + rl) * 512 + o16 * 8);
            *reinterpret_cast<bf16x8*>(Hs + rl * 1024 + ((o16 * 16) ^ ((rl & 7) << 4))) = v;
        }

        // ---- early coalesced epilogue loads (independent of LDS) ----
        const float* gxt = gxT + (size_t)t * 3072 * 128;
        const float* hTp = (t == 0) ? sesT : ((t & 1) ? hT0 : hT1);
        float pr[4], pz[4], gn[4], cn[4], hful[4];
#pragma unroll
        for (int i = 0; i < 4; ++i) {
            int jj = jbase + i;
            pr[i] = gxt[(size_t)jj * 128 + b_g];
            pz[i] = gxt[(size_t)(1024 + jj) * 128 + b_g];
            gn[i] = gxt[(size_t)(2048 + jj) * 128 + b_g];
            cn[i] = ghcT[(size_t)(2048 + jj) * 128 + b_g];
            hful[i] = (jj < 512) ? hTp[(size_t)jj * 128 + b_g]
                                 : sesT[(size_t)(jj - 512) * 128 + b_g];
        }
        __syncthreads();

        // ---- MFMA: acc[g] over K=512 ----
        f32x4 acc[3];
#pragma unroll
        for (int g = 0; g < 3; ++g) acc[g] = (f32x4){0.f, 0.f, 0.f, 0.f};
        const int hrow = wc * 16 + lrow;
        const int arow0 = wr * 16 + lrow;
        for (int kb = 0; kb < 16; ++kb) {
            int ko = kb * 64 + kq * 16;
            bf16x8 hfrag = *reinterpret_cast<const bf16x8*>(
                Hs + hrow * 1024 + (ko ^ ((hrow & 7) << 4)));
#pragma unroll
            for (int g = 0; g < 3; ++g) {
                int arow = g * 32 + arow0;
                bf16x8 wfrag = *reinterpret_cast<const bf16x8*>(
                    Ws + arow * 1024 + (ko ^ ((arow & 7) << 4)));
                acc[g] = __builtin_amdgcn_mfma_f32_16x16x32_bf16(
                    wfrag, hfrag, acc[g], 0, 0, 0);
            }
        }

        // ---- gates + stores (all coalesced except tiny h_bf scatter) ----
        float* hTw = (t & 1) ? hT1 : hT0;
        __bf16* hbw = (t & 1) ? hb1 : hb0;
#pragma unroll
        for (int i = 0; i < 4; ++i) {
            int jj = jbase + i;
            float r = 1.0f / (1.0f + expf(-(pr[i] + acc[0][i])));
            float z = 1.0f / (1.0f + expf(-(pz[i] + acc[1][i])));
            float nn = tanhf(gn[i] + r * (acc[2][i] + cn[i]));
            float hn = (1.0f - z) * nn + z * hful[i];
            hall[(size_t)(t * 128 + b_g) * 1024 + jj] = (__bf16)hn;
            if (writes_h) {
                hTw[(size_t)jj * 128 + b_g] = hn;
                hbw[(size_t)b_g * 512 + jj] = (__bf16)hn;
            }
        }

        // ---- grid barrier: 8 spaced counters + explicit fences ----
        if (t < 49) {
            __syncthreads();               // drains this block's stores (vmcnt 0)
            if (tid == 0) {
                __builtin_amdgcn_fence(__ATOMIC_RELEASE, "agent");
                __hip_atomic_fetch_add(&cnt[(bid & 7) * 32], 1u,
                                       __ATOMIC_RELAXED, __HIP_MEMORY_SCOPE_AGENT);
            }
            if (tid < 8) {
                unsigned tgt = (unsigned)(t + 1) * 16u;
                while (__hip_atomic_load(&cnt[tid * 32], __ATOMIC_RELAXED,
                                         __HIP_MEMORY_SCOPE_AGENT) < tgt)
                    __builtin_amdgcn_s_sleep(1);
            }
            __syncthreads();
            __builtin_amdgcn_fence(__ATOMIC_ACQUIRE, "agent");
        }
    }
}

// ---------------------------------------------------------------------------
extern "C" void kernel_launch(void* const* d_in, const int* in_sizes, int n_in,
                              void* d_out, int out_size, void* d_ws, size_t ws_size,
                              hipStream_t stream) {
    const float* ses_enc = (const float*)d_in[0];
    const int*   x       = (const int*)d_in[1];
    const float* emb     = (const float*)d_in[2];
    const float* Wih     = (const float*)d_in[3];
    const float* Whh     = (const float*)d_in[4];
    const float* bih     = (const float*)d_in[5];
    const float* bhh     = (const float*)d_in[6];
    const float* W1      = (const float*)d_in[7];
    const float* b1      = (const float*)d_in[8];
    const float* W2      = (const float*)d_in[9];
    const float* b2      = (const float*)d_in[10];
    const float* Wout    = (const float*)d_in[11];
    float* out = (float*)d_out;

    // ---- workspace layout (bytes) ----
    char* ws = (char*)d_ws;
    float*  sesT      = (float*)(ws + 0);          // 512*128*4   = 262144
    __bf16* ses_bf    = (__bf16*)(ws + 262144);    // 128*512*2   = 131072
    float*  ghcT      = (float*)(ws + 393216);     // 3072*128*4  = 1572864
    float*  hT0       = (float*)(ws + 1966080);    // 512*128*4
    float*  hT1       = (float*)(ws + 2228224);
    __bf16* hb0       = (__bf16*)(ws + 2490368);   // 128*512*2
    __bf16* hb1       = (__bf16*)(ws + 2621440);
    __bf16* o_bf      = (__bf16*)(ws + 2752512);   // 6400*320*2  = 4096000
    __bf16* W1_bf     = (__bf16*)(ws + 6848512);   // 512*1024*2
    __bf16* Whh_a_bf  = (__bf16*)(ws + 7897088);   // 3072*512*2
    __bf16* Whh_b_bf  = (__bf16*)(ws + 11042816);  // 3072*512*2
    __bf16* Wih_bf    = (__bf16*)(ws + 14188544);  // 3072*320*2
    __bf16* W2_bf     = (__bf16*)(ws + 16154624);  // 300*1024*2
    __bf16* Wout_bf   = (__bf16*)(ws + 16769024);  // 10112*320*2
    __bf16* sesenc_bf = (__bf16*)(ws + 23240704);  // 128*1024*2
    unsigned* cnt     = (unsigned*)(ws + 23502848); // 8 ctr * 128B

    // ---- d_out used as scratch, consumed before logits overwrite ----
    char* ob = (char*)d_out;
    float*  gxT     = (float*)ob;                  // 50*3072*128*4 = 78,643,200
    __bf16* emb_bf  = (__bf16*)(ob + 80000000);    // 6400*320*2
    __bf16* hall_bf = (__bf16*)(ob + 88000000);    // 6400*1024*2

    dim3 blk(256);
    auto cvt = [&](const float* src, int sr, int sc, int ss, int so,
                   __bf16* dst, int dr, int dc) {
        int total = dr * dc;
        cvt_kernel<<<(total + 255) / 256, 256, 0, stream>>>(src, sr, sc, ss, so, dst, dr, dc);
    };
    cvt(W1,      512, 1024, 1024, 0,   W1_bf,     512, 1024);
    cvt(Whh,    3072,  512, 1024, 0,   Whh_a_bf, 3072,  512);
    cvt(Whh,    3072,  512, 1024, 512, Whh_b_bf, 3072,  512);
    cvt(Wih,    3072,  300,  300, 0,   Wih_bf,   3072,  320);
    cvt(W2,      300, 1024, 1024, 0,   W2_bf,     300, 1024);
    cvt(Wout,  10004,  300,  300, 0,   Wout_bf, 10112,  320);
    cvt(ses_enc, 128, 1024, 1024, 0,   sesenc_bf, 128, 1024);
    emb_kernel<<<6400, 64, 0, stream>>>(x, emb, emb_bf);
    hipMemsetAsync(cnt, 0, 1024, stream);

    GemmParams P;

    // ses = tanh(ses_enc @ W1^T + b1) -> ses_bf [b][512] + sesT [512][b]
    P = {sesenc_bf, 1024, W1_bf, 1024, 512, 1024, b1, sesT, 512, 512, ses_bf,
         nullptr, nullptr, 0, 0};
    gemm_bt<1><<<dim3(1, 4), blk, 0, stream>>>(P);

    // ghcT[c][b] = (Whh[:,512:] @ ses^T) + bhh   (swapped: A=Whh_b, B=ses)
    P = {Whh_b_bf, 512, ses_bf, 512, 128, 512, bhh, ghcT, 0, 0, nullptr,
         nullptr, nullptr, 0, 0};
    gemm_bt<4><<<dim3(24, 1), blk, 0, stream>>>(P);

    // gxT[t][c][b] = (Wih @ emb^T) + bih (+ ghcT for c<2048)
    P = {Wih_bf, 320, emb_bf, 320, 6400, 320, bih, gxT, 3072 * 128, 0, nullptr,
         nullptr, ghcT, 0, 2048};
    gemm_bt<4><<<dim3(24, 50), blk, 0, stream>>>(P);

    // ---- fused persistent scan ----
    scan_kernel<<<SCAN_NB, 256, 0, stream>>>(
        Whh_a_bf, gxT, ghcT, sesT, ses_bf,
        hT0, hT1, hb0, hb1, hall_bf, cnt);

    // o = hall @ W2^T + b2 + emb  -> bf16, rows remapped (t,b)->(b,t)
    P = {hall_bf, 1024, W2_bf, 1024, 300, 1024, b2, nullptr, 0, 300, o_bf,
         emb_bf, nullptr, 0, 0};
    gemm_bt<2><<<dim3(50, 3), blk, 0, stream>>>(P);

    // logits = o @ Wout^T -> d_out f32 (overwrites all scratch regions)
    P = {o_bf, 320, Wout_bf, 320, 10112, 320, nullptr, out, 10004, 10004, nullptr,
         nullptr, nullptr, 0, 0};
    gemm_bt<3><<<dim3(50, 79), blk, 0, stream>>>(P);

    (void)in_sizes; (void)n_in; (void)out_size; (void)ws_size;
}

// Round 5
// 708.819 us; speedup vs baseline: 2.0324x; 1.2791x over previous
//
#include <hip/hip_runtime.h>

// ---------------------------------------------------------------------------
// Decoder (GRU, T=50 steps) on MI355X.
// Round 4: round-3 architecture with the F row-stride bug fixed.
//   - F is [51][128][1024] bf16 -> row = 2048 B = 256 u64. scan_kernel now
//     uses *256 u64 stride (was *128: read wrong rows, wrote half-stride).
//   - Scan computes ONLY the recurrent half (j<512): 64 blocks, 3 gates x 32 j
//     x 32 b per block; Whh slice 96KB LDS-resident; h exchanged via
//     fine-grained agent-scope relaxed atomics through the coherent point
//     (bypasses non-coherent per-XCD L2) -- no cache-flushing fences.
//   - 4 independent 16-block barrier groups (one per batch quarter).
//   - hprev carried in registers; ghc hoisted; gx[t+1] prefetched.
//   - Non-recurrent half hall[:,512:] deferred to a parallel tail kernel.
//   - h history F (d_out scratch) = exchange buf + o-GEMM input.
// Dims: V=10004 E=300 SH=1024 H=512 G=1024 B=128 T=50.
// ---------------------------------------------------------------------------

typedef __bf16 bf16x8 __attribute__((ext_vector_type(8)));
typedef float f32x4 __attribute__((ext_vector_type(4)));
typedef unsigned long long u64;

// ---------------- fp32 -> bf16 (padded) conversion -------------------------
__global__ void cvt_kernel(const float* __restrict__ src, int srows, int scols,
                           int sstride, int soff,
                           __bf16* __restrict__ dst, int drows, int dcols) {
    int idx = blockIdx.x * 256 + threadIdx.x;
    int total = drows * dcols;
    if (idx >= total) return;
    int r = idx / dcols, c = idx % dcols;
    float v = 0.0f;
    if (r < srows && c < scols) v = src[(size_t)r * sstride + soff + c];
    dst[idx] = (__bf16)v;
}

// ---------------- embedding gather -> bf16 [t*128+b][320] ------------------
__global__ void emb_kernel(const int* __restrict__ x, const float* __restrict__ emb,
                           __bf16* __restrict__ embbf) {
    int m = blockIdx.x;            // m = t*128 + b
    int t = m >> 7, b = m & 127;
    int tok = x[b * 50 + t];
    const float* src = emb + (size_t)tok * 300;
    for (int i = threadIdx.x; i < 320; i += 64) {
        float v = (i < 300) ? src[i] : 0.0f;
        embbf[(size_t)m * 320 + i] = (__bf16)v;
    }
}

// ---------------- generic bf16 MFMA GEMM: C = A @ B^T ----------------------
struct GemmParams {
    const __bf16* A; int lda;
    const __bf16* B; int ldb; int Brows;
    int K;
    const float* bias;
    float* outF; int ldo; int Nstore;   // EPI4: ldo = t-stride
    __bf16* outBf;
    const __bf16* res;     // EPI 2: residual (emb_bf), row-indexed like A
    const float* add2;     // EPI 4: transposed addend [r][128]
    int ld2; int add2lim;
};

// EPI: 1 = tanh, bf16 store (ldo) + f32 TRANSPOSED store   (ses -> F[0], sesT)
//      2 = bias + residual, bf16 store, row remap          (o)
//      3 = plain f32 store with col guard                  (logits)
//      4 = transposed f32 store: out[(c>>7)*ldo + r*128 + (c&127)]
//          (+bias[r], +add2[r*128+(c&127)] if r<add2lim)   (ghcT, gxT)
template <int EPI>
__launch_bounds__(256, 2)
__global__ void gemm_bt(GemmParams p) {
    __shared__ __bf16 As[128][40];
    __shared__ __bf16 Bs[128][40];

    const int tid = threadIdx.x;
    const int lane = tid & 63;
    const int wid = tid >> 6;
    const int wr = wid >> 1, wc = wid & 1;
    const int m0 = blockIdx.x * 128, c0 = blockIdx.y * 128;
    const int lrow = lane & 15;
    const int kq = lane >> 4;

    f32x4 acc[4][4];
#pragma unroll
    for (int i = 0; i < 4; ++i)
#pragma unroll
        for (int j = 0; j < 4; ++j) acc[i][j] = (f32x4){0.f, 0.f, 0.f, 0.f};

    for (int kb = 0; kb < p.K; kb += 32) {
#pragma unroll
        for (int i = 0; i < 2; ++i) {
            int chunk = i * 256 + tid;
            int row = chunk >> 2;
            int cc = (chunk & 3) * 8;
            bf16x8 va = *reinterpret_cast<const bf16x8*>(
                p.A + (size_t)(m0 + row) * p.lda + kb + cc);
            *reinterpret_cast<bf16x8*>(&As[row][cc]) = va;
            bf16x8 vb;
#pragma unroll
            for (int q = 0; q < 8; ++q) vb[q] = (__bf16)0.0f;
            int grow = c0 + row;
            if (grow < p.Brows)
                vb = *reinterpret_cast<const bf16x8*>(
                    p.B + (size_t)grow * p.ldb + kb + cc);
            *reinterpret_cast<bf16x8*>(&Bs[row][cc]) = vb;
        }
        __syncthreads();

        bf16x8 af[4], bfr[4];
#pragma unroll
        for (int m = 0; m < 4; ++m)
            af[m] = *reinterpret_cast<const bf16x8*>(&As[wr * 64 + m * 16 + lrow][kq * 8]);
#pragma unroll
        for (int n = 0; n < 4; ++n)
            bfr[n] = *reinterpret_cast<const bf16x8*>(&Bs[wc * 64 + n * 16 + lrow][kq * 8]);
#pragma unroll
        for (int m = 0; m < 4; ++m)
#pragma unroll
            for (int n = 0; n < 4; ++n)
                acc[m][n] = __builtin_amdgcn_mfma_f32_16x16x32_bf16(
                    af[m], bfr[n], acc[m][n], 0, 0, 0);
        __syncthreads();
    }

#pragma unroll
    for (int m = 0; m < 4; ++m) {
#pragma unroll
        for (int n = 0; n < 4; ++n) {
#pragma unroll
            for (int i = 0; i < 4; ++i) {
                int r = m0 + wr * 64 + m * 16 + kq * 4 + i;
                int c = c0 + wc * 64 + n * 16 + lrow;
                float v = acc[m][n][i];
                if constexpr (EPI == 1) {
                    v = tanhf(v + p.bias[c]);
                    p.outBf[(size_t)r * p.ldo + c] = (__bf16)v;
                    p.outF[(size_t)c * 128 + r] = v;          // sesT[hcol][b]
                } else if constexpr (EPI == 2) {
                    int ro = (r & 127) * 50 + (r >> 7);
                    if (c < 300) {
                        v += p.bias[c] + (float)p.res[(size_t)r * 320 + c];
                        p.outBf[(size_t)ro * 320 + c] = (__bf16)v;
                    } else if (c < 320) {
                        p.outBf[(size_t)ro * 320 + c] = (__bf16)0.0f;
                    }
                } else if constexpr (EPI == 3) {
                    if (c < p.Nstore) p.outF[(size_t)r * p.ldo + c] = v;
                } else {  // EPI == 4
                    if (c < p.Brows) {
                        float v2 = v + p.bias[r];
                        if (p.add2 && r < p.add2lim)
                            v2 += p.add2[(size_t)r * 128 + (c & 127)];
                        p.outF[(size_t)(c >> 7) * p.ldo + (size_t)r * 128 + (c & 127)] = v2;
                    }
                }
            }
        }
    }
}

// ---------------- persistent scan: recurrent half only ---------------------
// 64 blocks = 4 batch-quarters x 16 j-slices (j<512). Swapped MFMA:
// A=Whh rows (3 gates x 32 j), B=h rows (32 b), D[gaterow][batch].
// F viewed as u64: row = 256 u64 (= 1024 bf16 = 2048 B); recurrent half is
// u64 offsets [0,128) of each row.
#define SCAN_NB 64
__launch_bounds__(256, 1)
__global__ void scan_kernel(const __bf16* __restrict__ Whh_a,   // [3072][512]
                            const float* __restrict__ gxT,      // [50][3072][128]
                            const float* __restrict__ ghcT,     // [3072][128]
                            const float* __restrict__ sesT,     // [512][128] f32
                            u64* __restrict__ F,                // [51][128][256] u64
                            unsigned* __restrict__ cnt) {       // 4 ctr @ stride 32
    __shared__ char smem[131072];          // 96KB Whh + 32KB Hs, XOR-swizzled
    char* Ws = smem;
    char* Hs = smem + 98304;
    const int tid = threadIdx.x;
    const int lane = tid & 63;
    const int wid = tid >> 6;
    const int wr = wid >> 1, wc = wid & 1;
    const int bid = blockIdx.x;
    const int q = bid >> 4;                // batch quarter
    const int j0 = (bid & 15) * 32;        // hidden-col base (0..480)
    const int lrow = lane & 15, kq = lane >> 4;

    // ---- stage Whh slice once: rows {g*1024 + j0 + jj}, swizzled ----
    for (int it = 0; it < 24; ++it) {
        int c = it * 256 + tid;            // 0..6143 (16B chunks)
        int rl = c >> 6, o16 = c & 63;
        int g = rl >> 5, jj = rl & 31;
        bf16x8 v = *reinterpret_cast<const bf16x8*>(
            Whh_a + (size_t)(g * 1024 + j0 + jj) * 512 + o16 * 8);
        *reinterpret_cast<bf16x8*>(Ws + rl * 1024 + ((o16 * 16) ^ ((rl & 7) << 4))) = v;
    }

    const int b_g = q * 32 + wc * 16 + lrow;   // global batch col
    const int jbase = j0 + wr * 16 + kq * 4;   // global j base (<512)

    // ---- hoisted step-invariants + t=0 state/prefetch ----
    float cn[4], hprev[4], gcur[12], gpre[12];
#pragma unroll
    for (int i = 0; i < 4; ++i) {
        cn[i] = ghcT[(size_t)(2048 + jbase + i) * 128 + b_g];
        hprev[i] = sesT[(size_t)(jbase + i) * 128 + b_g];
    }
#pragma unroll
    for (int i = 0; i < 4; ++i) {
        gpre[i]     = gxT[(size_t)(jbase + i) * 128 + b_g];
        gpre[4 + i] = gxT[(size_t)(1024 + jbase + i) * 128 + b_g];
        gpre[8 + i] = gxT[(size_t)(2048 + jbase + i) * 128 + b_g];
    }

    for (int t = 0; t < 50; ++t) {
        // ---- stage h slice [32 b][512] via agent-scope 8B atomic loads ----
        for (int it = 0; it < 16; ++it) {
            int c = it * 256 + tid;        // 0..4095 8B-chunks (32 rows x 128)
            int rl = c >> 7, o8 = c & 127;
            u64 v = __hip_atomic_load(
                F + ((size_t)t * 128 + q * 32 + rl) * 256 + o8,
                __ATOMIC_RELAXED, __HIP_MEMORY_SCOPE_AGENT);
            *reinterpret_cast<u64*>(Hs + rl * 1024 + ((o8 * 8) ^ ((rl & 7) << 4))) = v;
        }
        // ---- rotate gx regs; prefetch t+1 ----
#pragma unroll
        for (int i = 0; i < 12; ++i) gcur[i] = gpre[i];
        {
            int tn = (t < 49) ? t + 1 : 49;
            const float* gxt = gxT + (size_t)tn * 3072 * 128;
#pragma unroll
            for (int i = 0; i < 4; ++i) {
                gpre[i]     = gxt[(size_t)(jbase + i) * 128 + b_g];
                gpre[4 + i] = gxt[(size_t)(1024 + jbase + i) * 128 + b_g];
                gpre[8 + i] = gxt[(size_t)(2048 + jbase + i) * 128 + b_g];
            }
        }
        __syncthreads();

        // ---- MFMA: acc[g] over K=512 ----
        f32x4 acc[3];
#pragma unroll
        for (int g = 0; g < 3; ++g) acc[g] = (f32x4){0.f, 0.f, 0.f, 0.f};
        const int hrow = wc * 16 + lrow;
        const int arow0 = wr * 16 + lrow;
        for (int kb = 0; kb < 16; ++kb) {
            int ko = kb * 64 + kq * 16;
            bf16x8 hfrag = *reinterpret_cast<const bf16x8*>(
                Hs + hrow * 1024 + (ko ^ ((hrow & 7) << 4)));
#pragma unroll
            for (int g = 0; g < 3; ++g) {
                int arow = g * 32 + arow0;
                bf16x8 wfrag = *reinterpret_cast<const bf16x8*>(
                    Ws + arow * 1024 + (ko ^ ((arow & 7) << 4)));
                acc[g] = __builtin_amdgcn_mfma_f32_16x16x32_bf16(
                    wfrag, hfrag, acc[g], 0, 0, 0);
            }
        }

        // ---- gates (all state in registers) + single 8B agent store ----
        union { u64 u; __bf16 h[4]; } pk;
#pragma unroll
        for (int i = 0; i < 4; ++i) {
            float r = 1.0f / (1.0f + expf(-(gcur[i] + acc[0][i])));
            float z = 1.0f / (1.0f + expf(-(gcur[4 + i] + acc[1][i])));
            float nn = tanhf(gcur[8 + i] + r * (acc[2][i] + cn[i]));
            float hn = (1.0f - z) * nn + z * hprev[i];
            hprev[i] = hn;
            pk.h[i] = (__bf16)hn;
        }
        __hip_atomic_store(
            F + ((size_t)(t + 1) * 128 + b_g) * 256 + (jbase >> 2), pk.u,
            __ATOMIC_RELAXED, __HIP_MEMORY_SCOPE_AGENT);

        // ---- 16-block group barrier (syncthreads drains stores first) ----
        if (t < 49) {
            __syncthreads();               // s_waitcnt vmcnt(0) before barrier
            if (tid == 0) {
                __hip_atomic_fetch_add(cnt + q * 32, 1u,
                                       __ATOMIC_RELAXED, __HIP_MEMORY_SCOPE_AGENT);
                unsigned tgt = (unsigned)(t + 1) * 16u;
                while (__hip_atomic_load(cnt + q * 32, __ATOMIC_RELAXED,
                                         __HIP_MEMORY_SCOPE_AGENT) < tgt)
                    __builtin_amdgcn_s_sleep(1);
            }
            __syncthreads();
        }
    }
}

// ---------------- deferred non-recurrent half (j in [512,1024)) ------------
// 320 blocks = 5 t-groups x 4 batch-quarters x 16 j-slices; no sync needed.
__launch_bounds__(256, 1)
__global__ void tail_kernel(const __bf16* __restrict__ Whh_a,   // [3072][512]
                            const float* __restrict__ gxT,
                            const float* __restrict__ ghcT,
                            const float* __restrict__ sesT,
                            __bf16* __restrict__ F) {           // [51][128][1024]
    __shared__ char smem[131072];
    char* Ws = smem;
    char* Hs = smem + 98304;
    const int tid = threadIdx.x;
    const int lane = tid & 63;
    const int wid = tid >> 6;
    const int wr = wid >> 1, wc = wid & 1;
    const int bid = blockIdx.x;
    const int tg = bid >> 6;               // 0..4
    const int rem = bid & 63;
    const int q = rem >> 4;
    const int j0 = 512 + (rem & 15) * 32;  // 512..992
    const int lrow = lane & 15, kq = lane >> 4;

    for (int it = 0; it < 24; ++it) {
        int c = it * 256 + tid;
        int rl = c >> 6, o16 = c & 63;
        int g = rl >> 5, jj = rl & 31;
        bf16x8 v = *reinterpret_cast<const bf16x8*>(
            Whh_a + (size_t)(g * 1024 + j0 + jj) * 512 + o16 * 8);
        *reinterpret_cast<bf16x8*>(Ws + rl * 1024 + ((o16 * 16) ^ ((rl & 7) << 4))) = v;
    }

    const int b_g = q * 32 + wc * 16 + lrow;
    const int jbase = j0 + wr * 16 + kq * 4;   // in [512,1024)

    float cn[4], sv[4];
#pragma unroll
    for (int i = 0; i < 4; ++i) {
        cn[i] = ghcT[(size_t)(2048 + jbase + i) * 128 + b_g];
        sv[i] = sesT[(size_t)(jbase + i - 512) * 128 + b_g];
    }

    for (int tt = tg * 10; tt < tg * 10 + 10; ++tt) {
        // stage h_tt (first half of F[tt], plain 16B loads)
        for (int it = 0; it < 8; ++it) {
            int c = it * 256 + tid;        // 0..2047
            int rl = c >> 6, o16 = c & 63;
            bf16x8 v = *reinterpret_cast<const bf16x8*>(
                F + ((size_t)tt * 128 + q * 32 + rl) * 1024 + o16 * 8);
            *reinterpret_cast<bf16x8*>(Hs + rl * 1024 + ((o16 * 16) ^ ((rl & 7) << 4))) = v;
        }
        const float* gxt = gxT + (size_t)tt * 3072 * 128;
        float g0[12];
#pragma unroll
        for (int i = 0; i < 4; ++i) {
            g0[i]     = gxt[(size_t)(jbase + i) * 128 + b_g];
            g0[4 + i] = gxt[(size_t)(1024 + jbase + i) * 128 + b_g];
            g0[8 + i] = gxt[(size_t)(2048 + jbase + i) * 128 + b_g];
        }
        __syncthreads();

        f32x4 acc[3];
#pragma unroll
        for (int g = 0; g < 3; ++g) acc[g] = (f32x4){0.f, 0.f, 0.f, 0.f};
        const int hrow = wc * 16 + lrow;
        const int arow0 = wr * 16 + lrow;
        for (int kb = 0; kb < 16; ++kb) {
            int ko = kb * 64 + kq * 16;
            bf16x8 hfrag = *reinterpret_cast<const bf16x8*>(
                Hs + hrow * 1024 + (ko ^ ((hrow & 7) << 4)));
#pragma unroll
            for (int g = 0; g < 3; ++g) {
                int arow = g * 32 + arow0;
                bf16x8 wfrag = *reinterpret_cast<const bf16x8*>(
                    Ws + arow * 1024 + (ko ^ ((arow & 7) << 4)));
                acc[g] = __builtin_amdgcn_mfma_f32_16x16x32_bf16(
                    wfrag, hfrag, acc[g], 0, 0, 0);
            }
        }

        union { u64 u; __bf16 h[4]; } pk;
#pragma unroll
        for (int i = 0; i < 4; ++i) {
            float r = 1.0f / (1.0f + expf(-(g0[i] + acc[0][i])));
            float z = 1.0f / (1.0f + expf(-(g0[4 + i] + acc[1][i])));
            float nn = tanhf(g0[8 + i] + r * (acc[2][i] + cn[i]));
            pk.h[i] = (__bf16)((1.0f - z) * nn + z * sv[i]);
        }
        *reinterpret_cast<u64*>(F + ((size_t)(tt + 1) * 128 + b_g) * 1024 + jbase) = pk.u;
        __syncthreads();                   // Hs WAR before next tt
    }
}

// ---------------------------------------------------------------------------
extern "C" void kernel_launch(void* const* d_in, const int* in_sizes, int n_in,
                              void* d_out, int out_size, void* d_ws, size_t ws_size,
                              hipStream_t stream) {
    const float* ses_enc = (const float*)d_in[0];
    const int*   x       = (const int*)d_in[1];
    const float* emb     = (const float*)d_in[2];
    const float* Wih     = (const float*)d_in[3];
    const float* Whh     = (const float*)d_in[4];
    const float* bih     = (const float*)d_in[5];
    const float* bhh     = (const float*)d_in[6];
    const float* W1      = (const float*)d_in[7];
    const float* b1      = (const float*)d_in[8];
    const float* W2      = (const float*)d_in[9];
    const float* b2      = (const float*)d_in[10];
    const float* Wout    = (const float*)d_in[11];
    float* out = (float*)d_out;

    // ---- workspace layout (bytes) ----
    char* ws = (char*)d_ws;
    float*  sesT      = (float*)(ws + 0);          // 512*128*4   = 262144
    float*  ghcT      = (float*)(ws + 262144);     // 3072*128*4  = 1572864
    __bf16* o_bf      = (__bf16*)(ws + 1835008);   // 6400*320*2  = 4096000
    __bf16* W1_bf     = (__bf16*)(ws + 5931008);   // 512*1024*2
    __bf16* Whh_a_bf  = (__bf16*)(ws + 6979584);   // 3072*512*2
    __bf16* Whh_b_bf  = (__bf16*)(ws + 10125312);  // 3072*512*2
    __bf16* Wih_bf    = (__bf16*)(ws + 13271040);  // 3072*320*2
    __bf16* W2_bf     = (__bf16*)(ws + 15237120);  // 300*1024*2
    __bf16* Wout_bf   = (__bf16*)(ws + 15851520);  // 10112*320*2
    __bf16* sesenc_bf = (__bf16*)(ws + 22323200);  // 128*1024*2
    unsigned* cnt     = (unsigned*)(ws + 22585344); // 4 ctr * 128B

    // ---- d_out used as scratch, consumed before logits overwrite ----
    char* ob = (char*)d_out;
    float*  gxT     = (float*)ob;                  // 50*3072*128*4 = 78,643,200
    __bf16* emb_bf  = (__bf16*)(ob + 80000000);    // 6400*320*2
    __bf16* F       = (__bf16*)(ob + 88000000);    // 51*128*1024*2 = 13,369,344

    dim3 blk(256);
    auto cvt = [&](const float* src, int sr, int sc, int ss, int so,
                   __bf16* dst, int dr, int dc) {
        int total = dr * dc;
        cvt_kernel<<<(total + 255) / 256, 256, 0, stream>>>(src, sr, sc, ss, so, dst, dr, dc);
    };
    cvt(W1,      512, 1024, 1024, 0,   W1_bf,     512, 1024);
    cvt(Whh,    3072,  512, 1024, 0,   Whh_a_bf, 3072,  512);
    cvt(Whh,    3072,  512, 1024, 512, Whh_b_bf, 3072,  512);
    cvt(Wih,    3072,  300,  300, 0,   Wih_bf,   3072,  320);
    cvt(W2,      300, 1024, 1024, 0,   W2_bf,     300, 1024);
    cvt(Wout,  10004,  300,  300, 0,   Wout_bf, 10112,  320);
    cvt(ses_enc, 128, 1024, 1024, 0,   sesenc_bf, 128, 1024);
    emb_kernel<<<6400, 64, 0, stream>>>(x, emb, emb_bf);
    hipMemsetAsync(cnt, 0, 1024, stream);

    GemmParams P;

    // ses = tanh(ses_enc @ W1^T + b1) -> F[0][b][0:512] bf16 + sesT [512][b] f32
    P = {sesenc_bf, 1024, W1_bf, 1024, 512, 1024, b1, sesT, 1024, 512, F,
         nullptr, nullptr, 0, 0};
    gemm_bt<1><<<dim3(1, 4), blk, 0, stream>>>(P);

    // ghcT[c][b] = (Whh[:,512:] @ ses^T) + bhh   (swapped: A=Whh_b, B=F[0])
    P = {Whh_b_bf, 512, F, 1024, 128, 512, bhh, ghcT, 0, 0, nullptr,
         nullptr, nullptr, 0, 0};
    gemm_bt<4><<<dim3(24, 1), blk, 0, stream>>>(P);

    // gxT[t][c][b] = (Wih @ emb^T) + bih (+ ghcT for c<2048)
    P = {Wih_bf, 320, emb_bf, 320, 6400, 320, bih, gxT, 3072 * 128, 0, nullptr,
         nullptr, ghcT, 0, 2048};
    gemm_bt<4><<<dim3(24, 50), blk, 0, stream>>>(P);

    // ---- persistent scan (recurrent half) ----
    scan_kernel<<<SCAN_NB, 256, 0, stream>>>(
        Whh_a_bf, gxT, ghcT, sesT, (u64*)F, cnt);

    // ---- deferred non-recurrent half ----
    tail_kernel<<<320, 256, 0, stream>>>(Whh_a_bf, gxT, ghcT, sesT, F);

    // o = hnew @ W2^T + b2 + emb  -> bf16, rows remapped (t,b)->(b,t)
    P = {F + 128 * 1024, 1024, W2_bf, 1024, 300, 1024, b2, nullptr, 0, 300, o_bf,
         emb_bf, nullptr, 0, 0};
    gemm_bt<2><<<dim3(50, 3), blk, 0, stream>>>(P);

    // logits = o @ Wout^T -> d_out f32 (overwrites all scratch regions)
    P = {o_bf, 320, Wout_bf, 320, 10112, 320, nullptr, out, 10004, 10004, nullptr,
         nullptr, nullptr, 0, 0};
    gemm_bt<3><<<dim3(50, 79), blk, 0, stream>>>(P);

    (void)in_sizes; (void)n_in; (void)out_size; (void)ws_size;
}